// Round 6
// baseline (1730.011 us; speedup 1.0000x reference)
//
#include <hip/hip_runtime.h>

// ---- problem constants ----
#define N_MOLS  2000
#define APM     50
#define N_ATOMS 100001
#define N_BONDS 200001
#define MAX_NB  6
#define AF      133
#define BF      147
#define H       300

// ---- padded layout ----
#define SB    304      // hidden-row stride (fp16 / fp8 elements); 38*8
#define SF    152      // feature-row stride (fp16); 19*8
#define MB_P  200192   // bonds padded to x256 (782*256)
#define MA_P  100096   // atoms padded to x256 (391*256)
#define SWH   320      // Wt_h K-rows per col
#define SWI   160      // Wt_i
#define SWO   480      // Wt_o ([amsg 320 | fa 160])

typedef _Float16 f16x8 __attribute__((ext_vector_type(8)));
typedef float    f32x4 __attribute__((ext_vector_type(4)));

// ---------------- fp8 e4m3 helpers (OCP fn, via fp16, flush-denorm) ----------------
__device__ inline unsigned int f16_to_fp8(_Float16 h) {
    union { _Float16 h; unsigned short u; } cv; cv.h = h;
    const unsigned short u = cv.u;
    const int s = (u >> 15) & 1;
    const int e = (u >> 10) & 31;
    const int m = u & 1023;
    int e8 = e - 8;                       // e - 15 + 7
    if (e8 <= 0) return s << 7;           // underflow/denorm -> 0 (|v| < 2^-6)
    int m8 = (m + 64) >> 7;               // round-nearest
    if (m8 == 8) { m8 = 0; e8 += 1; }
    if (e8 > 15 || (e8 == 15 && m8 > 6)) return (s << 7) | 0x7E;  // clamp 448
    return (s << 7) | (e8 << 3) | m8;
}
__device__ inline float fp8_to_f32(unsigned int c) {
    const int s = (c >> 7) & 1, e = (c >> 3) & 15, m = c & 7;
    if (e == 0) return 0.f;
    union { unsigned short u; _Float16 h; } cv;
    cv.u = (unsigned short)((s << 15) | ((e + 8) << 10) | (m << 7));
    return (float)cv.h;
}

// ---------------- cast / prep ----------------
__global__ void cast_fb_kernel(const float* __restrict__ src, _Float16* __restrict__ dst) {
    unsigned i = blockIdx.x * blockDim.x + threadIdx.x;
    if (i >= (unsigned)MB_P * SF) return;
    unsigned m = i / SF, k = i % SF;
    dst[i] = (_Float16)((m < N_BONDS && k < BF) ? src[(size_t)m * BF + k] : 0.f);
}
__global__ void cast_fa_kernel(const float* __restrict__ src, _Float16* __restrict__ dst) {
    unsigned i = blockIdx.x * blockDim.x + threadIdx.x;
    if (i >= (unsigned)MA_P * SF) return;
    unsigned m = i / SF, k = i % SF;
    dst[i] = (_Float16)((m < N_ATOMS && k < AF) ? src[(size_t)m * AF + k] : 0.f);
}
__global__ void cast_wh_kernel(const float* __restrict__ W, _Float16* __restrict__ Wt) {
    int i = blockIdx.x * blockDim.x + threadIdx.x;
    if (i >= 320 * SWH) return;
    int n = i / SWH, k = i % SWH;
    Wt[i] = (_Float16)((n < H && k < H) ? W[k * H + n] : 0.f);
}
__global__ void cast_wi_kernel(const float* __restrict__ W, _Float16* __restrict__ Wt) {
    int i = blockIdx.x * blockDim.x + threadIdx.x;
    if (i >= 320 * SWI) return;
    int n = i / SWI, k = i % SWI;
    Wt[i] = (_Float16)((n < H && k < BF) ? W[k * H + n] : 0.f);
}
// A order for output GEMM: [a_message(320) | f_atoms(160)]; W_o rows 0..132 = f_atoms, 133..432 = a_message
__global__ void cast_wo_kernel(const float* __restrict__ W, _Float16* __restrict__ Wt) {
    int i = blockIdx.x * blockDim.x + threadIdx.x;
    if (i >= 320 * SWO) return;
    int n = i / SWO, r = i % SWO;
    float v = 0.f;
    if (n < H) {
        if (r < 320) { if (r < H) v = W[(AF + r) * H + n]; }
        else         { int rr = r - 320; if (rr < AF) v = W[rr * H + n]; }
    }
    Wt[i] = (_Float16)v;
}

// ---------------- dense one-pass GEMM, W in LDS once, coalesced epilogue ----------------
// Block 256 = 4 waves; block tile 256 rows x 80 cols (4 col-quarter blocks per row tile,
// adjacent blockIdx for L2 reuse of A). Wave = 64 rows x 80 cols, acc[4][5].
// LDS: W-slice [80 cols][K+8] (2-way bank alias only = free) + per-wave C-tile [16x80]
// for the coalesced write-back (R5's scattered 32B/16B store segments caused 1.86x
// WRITE inflation and 221us MODE0).
// Frag layout (16x16x32_f16): A[m=lane&15][k=quad*8+j], B=W[n=lane&15][k=...],
// D row=quad*4+e, col=lane&15.
// MODE 0 (I): A1=fb16(SF), K=160 : out8 = fp8(acc) [inp], out16 = relu(acc) [msg0]
// MODE 1 (H): A1=msg(SB),  K=320 : out16 = acc (linear) [hb]
// MODE 2 (O): A1=hm(SB) K0..319, A2=fa16(SF) K320..479 : out16 = relu(acc + bias)
template<int NCHUNK, int MODE>
__global__ __launch_bounds__(256, 2) void dgemm_kernel(
    const _Float16* __restrict__ A1, const _Float16* __restrict__ A2,
    const _Float16* __restrict__ Wt, const float* __restrict__ bias,
    _Float16* __restrict__ out16, unsigned char* __restrict__ out8)
{
    constexpr int K   = NCHUNK * 32;
    constexpr int STR = K + 8;                    // halfwords
    constexpr int KC8 = K / 8;                    // 16B chunks per col
    constexpr int SW  = (MODE == 0) ? SWI : (MODE == 1 ? SWH : SWO);
    __shared__ __align__(16) _Float16 Bs[80 * STR];
    __shared__ __align__(16) _Float16 Cs[4][16 * 80];

    const int tid  = threadIdx.x;
    const int lane = tid & 63, wave = tid >> 6;
    const int r16  = lane & 15, quad = lane >> 4;
    const int tile = blockIdx.x >> 2, quarter = blockIdx.x & 3;
    const int colbase = quarter * 80;

    // ---- stage this block's 80-col W slice into LDS (once) ----
    for (int idx = tid; idx < 80 * KC8; idx += 256) {
        const int c  = idx / KC8;
        const int kk = (idx - c * KC8) * 8;
        *(f16x8*)(&Bs[c * STR + kk]) = *(const f16x8*)(Wt + (size_t)(colbase + c) * SW + kk);
    }
    __syncthreads();

    const int row0 = tile * 256 + wave * 64;      // wave's 64-row strip

    f32x4 acc[4][5];
    #pragma unroll
    for (int s = 0; s < 4; ++s)
        #pragma unroll
        for (int ct = 0; ct < 5; ++ct) acc[s][ct] = f32x4{0.f, 0.f, 0.f, 0.f};

    #pragma unroll
    for (int kc = 0; kc < NCHUNK; ++kc) {
        const _Float16* ap; int kl, sa;
        if (MODE == 2 && kc >= 10) { ap = A2; kl = kc - 10; sa = SF; }
        else                       { ap = A1; kl = kc; sa = (MODE == 0 ? SF : SB); }
        f16x8 a[4];
        #pragma unroll
        for (int s = 0; s < 4; ++s)
            a[s] = *(const f16x8*)(ap + (size_t)(row0 + s * 16 + r16) * sa + kl * 32 + quad * 8);
        #pragma unroll
        for (int ct = 0; ct < 5; ++ct) {
            const f16x8 b = *(const f16x8*)(&Bs[(ct * 16 + r16) * STR + kc * 32 + quad * 8]);
            #pragma unroll
            for (int s = 0; s < 4; ++s)
                acc[s][ct] = __builtin_amdgcn_mfma_f32_16x16x32_f16(a[s], b, acc[s][ct], 0, 0, 0);
        }
    }

    // ---- epilogue: per 16-row group, stage in per-wave LDS tile, read back coalesced ----
    #pragma unroll 1
    for (int s = 0; s < 4; ++s) {
        // scatter acc -> Cs[wave] (16 rows x 80 cols); bank-conflict-free (verified pattern)
        #pragma unroll
        for (int ct = 0; ct < 5; ++ct)
            #pragma unroll
            for (int e = 0; e < 4; ++e)
                Cs[wave][(quad * 4 + e) * 80 + ct * 16 + r16] = (_Float16)acc[s][ct][e];
        // read back row-contiguous: 16 rows x 10 chunks of 8 halfwords
        #pragma unroll
        for (int i = 0; i < 3; ++i) {
            const int idx = i * 64 + lane;
            if (idx < 160) {
                const int row = idx / 10, c8 = idx - row * 10;
                const int col = colbase + c8 * 8;
                if (col < SB) {                       // chunks never straddle 304
                    const int rg = row0 + s * 16 + row;
                    const f16x8 v = *(const f16x8*)(&Cs[wave][row * 80 + c8 * 8]);
                    if (MODE == 0) {
                        f16x8 r;
                        unsigned long long pk = 0;
                        #pragma unroll
                        for (int j = 0; j < 8; ++j) {
                            r[j] = (_Float16)(v[j] > (_Float16)0.f ? v[j] : (_Float16)0.f);
                            pk |= (unsigned long long)f16_to_fp8(v[j]) << (8 * j);
                        }
                        *(f16x8*)(out16 + (size_t)rg * SB + col) = r;
                        *(unsigned long long*)(out8 + (size_t)rg * SB + col) = pk;
                    } else if (MODE == 1) {
                        *(f16x8*)(out16 + (size_t)rg * SB + col) = v;
                    } else {
                        f16x8 r;
                        #pragma unroll
                        for (int j = 0; j < 8; ++j) {
                            const int cj = col + j;
                            const float f = (float)v[j] + ((cj < H) ? bias[cj] : 0.f);
                            r[j] = (_Float16)(f > 0.f ? f : 0.f);
                        }
                        *(f16x8*)(out16 + (size_t)rg * SB + col) = r;
                    }
                }
            }
        }
    }
}

// ---------------- aggregate: dst[a][:] = sum_k w_bonds[a2b[a][k]] * src[a2b[a][k]][:] ----------------
__global__ __launch_bounds__(256, 8) void aggregate_kernel(
    const _Float16* __restrict__ src,
    const int* __restrict__ a2b,
    const float* __restrict__ w_bonds,
    _Float16* __restrict__ dst)
{
    const int lane = threadIdx.x & 63;
    const int a = blockIdx.x * 4 + (threadIdx.x >> 6);
    if (a >= N_ATOMS || lane >= 38) return;
    const int h0 = lane * 8;
    float acc[8] = {0, 0, 0, 0, 0, 0, 0, 0};
    #pragma unroll
    for (int k = 0; k < MAX_NB; ++k) {
        const int b = a2b[a * MAX_NB + k];
        const float w = w_bonds[b];
        const f16x8 m = *(const f16x8*)(src + (size_t)b * SB + h0);
        #pragma unroll
        for (int j = 0; j < 8; ++j) acc[j] += w * (float)m[j];
    }
    f16x8 o;
    #pragma unroll
    for (int j = 0; j < 8; ++j) o[j] = (_Float16)acc[j];
    *(f16x8*)(dst + (size_t)a * SB + h0) = o;
}

// ---------------- bond update: msg[b] = relu(inp[b] + hm[b2a[b]] - w_b * hb[b2revb[b]]) ----------------
__global__ __launch_bounds__(256, 8) void update_kernel(
    const unsigned char* __restrict__ inp8,
    const _Float16* __restrict__ hm,
    const _Float16* __restrict__ hb,
    const int* __restrict__ b2a,
    const int* __restrict__ b2revb,
    const float* __restrict__ w_bonds,
    _Float16* __restrict__ msg)
{
    const int lane = threadIdx.x & 63;
    const int b = blockIdx.x * 4 + (threadIdx.x >> 6);
    if (b >= MB_P || lane >= 38) return;
    const bool real = b < N_BONDS;
    const int bc = real ? b : 0;
    const int a  = b2a[bc];
    const int rb = b2revb[bc];
    const float w = w_bonds[bc];
    const int h0 = lane * 8;
    const uint2 i8  = *(const uint2*)(inp8 + (size_t)b * SB + h0);
    const f16x8 hmv = *(const f16x8*)(hm + (size_t)a  * SB + h0);
    const f16x8 hbv = *(const f16x8*)(hb + (size_t)rb * SB + h0);
    f16x8 o;
    #pragma unroll
    for (int j = 0; j < 8; ++j) {
        const unsigned int c = ((j < 4 ? i8.x : i8.y) >> (8 * (j & 3))) & 255u;
        const float v = fp8_to_f32(c) + (float)hmv[j] - w * (float)hbv[j];
        o[j] = (_Float16)((real && v > 0.f) ? v : 0.f);
    }
    *(f16x8*)(msg + (size_t)b * SB + h0) = o;
}

// ---------------- readout ----------------
__global__ __launch_bounds__(256, 8) void readout_kernel(
    const _Float16* __restrict__ ah,
    const float* __restrict__ w_atoms,
    const float* __restrict__ dop,
    float* __restrict__ out)
{
    const int lane = threadIdx.x & 63;
    const int m = blockIdx.x * 4 + (threadIdx.x >> 6);
    if (m >= N_MOLS || lane >= 38) return;
    const int h0 = lane * 8;
    const int a0 = 1 + m * APM;
    float acc[8] = {0, 0, 0, 0, 0, 0, 0, 0};
    float wsum = 0.f;
    for (int i = 0; i < APM; ++i) {
        const float w = w_atoms[a0 + i];
        wsum += w;
        const f16x8 v = *(const f16x8*)(ah + (size_t)(a0 + i) * SB + h0);
        #pragma unroll
        for (int j = 0; j < 8; ++j) acc[j] += w * (float)v[j];
    }
    const float s = dop[m] / wsum;
    #pragma unroll
    for (int j = 0; j < 8; ++j) {
        const int h = h0 + j;
        if (h < H) out[(size_t)m * H + h] = s * acc[j];
    }
}

// ---------------- launch ----------------
extern "C" void kernel_launch(void* const* d_in, const int* in_sizes, int n_in,
                              void* d_out, int out_size, void* d_ws, size_t ws_size,
                              hipStream_t stream) {
    const float* f_atoms = (const float*)d_in[0];
    const float* f_bonds = (const float*)d_in[1];
    const float* w_atoms = (const float*)d_in[2];
    const float* w_bonds = (const float*)d_in[3];
    const float* dop     = (const float*)d_in[4];
    const float* W_i     = (const float*)d_in[5];
    const float* W_h     = (const float*)d_in[6];
    const float* W_o     = (const float*)d_in[7];
    const float* b_o     = (const float*)d_in[8];
    const int* a2b    = (const int*)d_in[9];
    const int* b2a    = (const int*)d_in[10];
    const int* b2revb = (const int*)d_in[11];
    float* out = (float*)d_out;

    char* p = (char*)d_ws;
    auto alloc = [&](size_t bytes) {
        char* q = p;
        p += ((bytes + 64 /*tail pad for K-overreads*/ + 255) / 256) * 256;
        return q;
    };
    unsigned char* inp8 = (unsigned char*)alloc((size_t)MB_P * SB);          // 60.9 MB
    _Float16* msg  = (_Float16*)alloc((size_t)MB_P * SB * 2);                // 121.7 MB
    _Float16* hb   = (_Float16*)alloc((size_t)MB_P * SB * 2);                // 121.7 MB
    _Float16* hm   = (_Float16*)alloc((size_t)MA_P * SB * 2);                // 60.9 MB
    _Float16* Wth  = (_Float16*)alloc((size_t)320 * SWH * 2);
    _Float16* Wti  = (_Float16*)alloc((size_t)320 * SWI * 2);
    _Float16* Wto  = (_Float16*)alloc((size_t)320 * SWO * 2);                // total ~366 MB
    _Float16* fb16 = hb;                    // fb16 (61 MB) lives in hb until first layer GEMM
    _Float16* fa16 = (_Float16*)inp8;       // fa16 (30 MB) lives in inp8 after last update
    _Float16* ah   = hb;                    // output-GEMM result reuses dead hb

    if ((size_t)(p - (char*)d_ws) > ws_size) {   // clean failure instead of fault
        hipMemsetAsync(d_out, 0, (size_t)out_size * sizeof(float), stream);
        return;
    }

    // casts
    {
        unsigned n1 = (unsigned)MB_P * SF;
        cast_fb_kernel<<<(n1 + 255) / 256, 256, 0, stream>>>(f_bonds, fb16);
        cast_wh_kernel<<<(320 * SWH + 255) / 256, 256, 0, stream>>>(W_h, Wth);
        cast_wi_kernel<<<(320 * SWI + 255) / 256, 256, 0, stream>>>(W_i, Wti);
        cast_wo_kernel<<<(320 * SWO + 255) / 256, 256, 0, stream>>>(W_o, Wto);
    }

    const int gB = (MB_P / 256) * 4;      // 3128 (tile*4 + colquarter)
    const int gA = (MA_P / 256) * 4;      // 1564
    const int aggGrid = (N_ATOMS + 3) / 4;
    const int updGrid = MB_P / 4;

    // inp = fb @ W_i (fp8), msg0 = relu(inp)
    dgemm_kernel<5, 0><<<gB, 256, 0, stream>>>(fb16, nullptr, Wti, nullptr, msg, inp8);
    for (int d = 0; d < 3; ++d) {
        // hb = msg @ W_h  (dense, linear)
        dgemm_kernel<10, 1><<<gB, 256, 0, stream>>>(msg, nullptr, Wth, nullptr, hb, nullptr);
        // hm[a] = sum w * hb[a2b]
        aggregate_kernel<<<aggGrid, 256, 0, stream>>>(hb, a2b, w_bonds, hm);
        // msg = relu(inp + hm[b2a] - w * hb[b2revb])   (in place)
        update_kernel<<<updGrid, 256, 0, stream>>>(inp8, hm, hb, b2a, b2revb, w_bonds, msg);
    }
    // final atom aggregation from msg
    aggregate_kernel<<<aggGrid, 256, 0, stream>>>(msg, a2b, w_bonds, hm);
    // fa cast into (dead) inp8 region
    {
        unsigned n2 = (unsigned)MA_P * SF;
        cast_fa_kernel<<<(n2 + 255) / 256, 256, 0, stream>>>(f_atoms, fa16);
    }
    // ah = relu([hm | fa] @ W_o + b_o)
    dgemm_kernel<15, 2><<<gA, 256, 0, stream>>>(hm, fa16, Wto, b_o, ah, nullptr);
    readout_kernel<<<(N_MOLS + 3) / 4, 256, 0, stream>>>(ah, w_atoms, dop, out);
}

// Round 7
// 1297.041 us; speedup vs baseline: 1.3338x; 1.3338x over previous
//
#include <hip/hip_runtime.h>

// ---- problem constants ----
#define N_MOLS  2000
#define APM     50
#define N_ATOMS 100001
#define N_BONDS 200001
#define MAX_NB  6
#define AF      133
#define BF      147
#define H       300

// ---- padded layout ----
// SB=320 / SF=160: rows are 640/320 bytes = exact 64B-sector multiples -> no
// partial-sector RMW on writes, fully aligned gathers. (R6's SB=304 + col-split
// blocks caused 2-3x write inflation + 4x A re-fetch across XCD L2s.)
#define SB    320
#define SF    160
#define MB_P  200192   // bonds padded to x128 (1564*128)
#define MA_P  100096   // atoms padded to x128 (782*128)
#define SWH   320      // Wt_h K-rows per col
#define SWI   160      // Wt_i
#define SWO   480      // Wt_o ([amsg 320 | fa 160])

typedef _Float16 f16x8 __attribute__((ext_vector_type(8)));
typedef float    f32x4 __attribute__((ext_vector_type(4)));

// ---------------- fp8 e4m3 helpers (OCP fn, via fp16, flush-denorm) ----------------
__device__ inline unsigned int f16_to_fp8(_Float16 h) {
    union { _Float16 h; unsigned short u; } cv; cv.h = h;
    const unsigned short u = cv.u;
    const int s = (u >> 15) & 1;
    const int e = (u >> 10) & 31;
    const int m = u & 1023;
    int e8 = e - 8;                       // e - 15 + 7
    if (e8 <= 0) return s << 7;           // underflow/denorm -> 0 (|v| < 2^-6)
    int m8 = (m + 64) >> 7;               // round-nearest
    if (m8 == 8) { m8 = 0; e8 += 1; }
    if (e8 > 15 || (e8 == 15 && m8 > 6)) return (s << 7) | 0x7E;  // clamp 448
    return (s << 7) | (e8 << 3) | m8;
}
__device__ inline float fp8_to_f32(unsigned int c) {
    const int s = (c >> 7) & 1, e = (c >> 3) & 15, m = c & 7;
    if (e == 0) return 0.f;
    union { unsigned short u; _Float16 h; } cv;
    cv.u = (unsigned short)((s << 15) | ((e + 8) << 10) | (m << 7));
    return (float)cv.h;
}

// ---------------- cast / prep ----------------
__global__ void cast_fb_kernel(const float* __restrict__ src, _Float16* __restrict__ dst) {
    unsigned i = blockIdx.x * blockDim.x + threadIdx.x;
    if (i >= (unsigned)MB_P * SF) return;
    unsigned m = i / SF, k = i % SF;
    dst[i] = (_Float16)((m < N_BONDS && k < BF) ? src[(size_t)m * BF + k] : 0.f);
}
__global__ void cast_fa_kernel(const float* __restrict__ src, _Float16* __restrict__ dst) {
    unsigned i = blockIdx.x * blockDim.x + threadIdx.x;
    if (i >= (unsigned)MA_P * SF) return;
    unsigned m = i / SF, k = i % SF;
    dst[i] = (_Float16)((m < N_ATOMS && k < AF) ? src[(size_t)m * AF + k] : 0.f);
}
__global__ void cast_wh_kernel(const float* __restrict__ W, _Float16* __restrict__ Wt) {
    int i = blockIdx.x * blockDim.x + threadIdx.x;
    if (i >= 320 * SWH) return;
    int n = i / SWH, k = i % SWH;
    Wt[i] = (_Float16)((n < H && k < H) ? W[k * H + n] : 0.f);
}
__global__ void cast_wi_kernel(const float* __restrict__ W, _Float16* __restrict__ Wt) {
    int i = blockIdx.x * blockDim.x + threadIdx.x;
    if (i >= 320 * SWI) return;
    int n = i / SWI, k = i % SWI;
    Wt[i] = (_Float16)((n < H && k < BF) ? W[k * H + n] : 0.f);
}
// A order for output GEMM: [a_message(320) | f_atoms(160)]; W_o rows 0..132 = f_atoms, 133..432 = a_message
__global__ void cast_wo_kernel(const float* __restrict__ W, _Float16* __restrict__ Wt) {
    int i = blockIdx.x * blockDim.x + threadIdx.x;
    if (i >= 320 * SWO) return;
    int n = i / SWO, r = i % SWO;
    float v = 0.f;
    if (n < H) {
        if (r < 320) { if (r < H) v = W[(AF + r) * H + n]; }
        else         { int rr = r - 320; if (rr < AF) v = W[rr * H + n]; }
    }
    Wt[i] = (_Float16)v;
}

// ---------------- dense GEMM: 128 rows x FULL 320 cols per block ----------------
// 4 waves: wave = 64 rows x 160 cols (acc[4][10]); full-row output per block
// -> ideal WRITE (R4-verified); A read once per block -> L3-friendly FETCH.
// W double-buffered in LDS per 32-K chunk, ONE barrier per chunk.
// LDS col stride 40 halfwords (20 words, odd multiplier) -> even bank spread.
// Frag layout (16x16x32_f16): A[m=lane&15][k=quad*8+j], B=W[n=lane&15][k=...],
// D row=quad*4+e, col=lane&15.
// MODE 0 (I): A1=fb16(SF), K=160 : out8 = fp8(acc) [pre-relu inp], out16 = relu(acc)
// MODE 1 (H): A1=msg(SB),  K=320 : out16 = acc (linear) [hb]
// MODE 2 (O): A1=hm(SB) K0..319, A2=fa16(SF) K320..479 : out16 = relu(acc + bias)
template<int NCHUNK, int MODE>
__global__ __launch_bounds__(256, 2) void dgemm_kernel(
    const _Float16* __restrict__ A1, const _Float16* __restrict__ A2,
    const _Float16* __restrict__ Wt, const float* __restrict__ bias,
    _Float16* __restrict__ out16, unsigned char* __restrict__ out8)
{
    constexpr int SW = (MODE == 0) ? SWI : (MODE == 1 ? SWH : SWO);
    __shared__ __align__(16) _Float16 Bs[2][320 * 40];

    const int tid  = threadIdx.x;
    const int lane = tid & 63, wave = tid >> 6;
    const int r16  = lane & 15, quad = lane >> 4;
    const int rowhalf = wave >> 1, colhalf = wave & 1;
    const int row0 = blockIdx.x * 128 + rowhalf * 64;
    const int colb = colhalf * 160;

    // ---- stage chunk 0 ----
    #pragma unroll
    for (int i = 0; i < 5; ++i) {
        const int idx = tid + i * 256;           // < 1280
        const int c = idx >> 2, part = idx & 3;
        *(f16x8*)(&Bs[0][c * 40 + part * 8]) =
            *(const f16x8*)(Wt + (size_t)c * SW + part * 8);
    }
    __syncthreads();

    f32x4 acc[4][10];
    #pragma unroll
    for (int s = 0; s < 4; ++s)
        #pragma unroll
        for (int ct = 0; ct < 10; ++ct) acc[s][ct] = f32x4{0.f, 0.f, 0.f, 0.f};

    #pragma unroll
    for (int kc = 0; kc < NCHUNK; ++kc) {
        const int cur = kc & 1;
        // prefetch next W chunk into registers (overlaps MFMA below)
        f16x8 st[5];
        if (kc + 1 < NCHUNK) {
            #pragma unroll
            for (int i = 0; i < 5; ++i) {
                const int idx = tid + i * 256;
                const int c = idx >> 2, part = idx & 3;
                st[i] = *(const f16x8*)(Wt + (size_t)c * SW + (kc + 1) * 32 + part * 8);
            }
        }
        // A fragments for this chunk
        const _Float16* ap; int kl, sa;
        if (MODE == 2 && kc >= 10) { ap = A2; kl = kc - 10; sa = SF; }
        else                       { ap = A1; kl = kc; sa = (MODE == 0 ? SF : SB); }
        f16x8 a[4];
        #pragma unroll
        for (int s = 0; s < 4; ++s)
            a[s] = *(const f16x8*)(ap + (size_t)(row0 + s * 16 + r16) * sa + kl * 32 + quad * 8);
        // MFMA over this wave's 10 col-strips
        #pragma unroll
        for (int ct = 0; ct < 10; ++ct) {
            const f16x8 b = *(const f16x8*)(&Bs[cur][(colb + ct * 16 + r16) * 40 + quad * 8]);
            #pragma unroll
            for (int s = 0; s < 4; ++s)
                acc[s][ct] = __builtin_amdgcn_mfma_f32_16x16x32_f16(a[s], b, acc[s][ct], 0, 0, 0);
        }
        // commit prefetched chunk to the other buffer
        if (kc + 1 < NCHUNK) {
            #pragma unroll
            for (int i = 0; i < 5; ++i) {
                const int idx = tid + i * 256;
                const int c = idx >> 2, part = idx & 3;
                *(f16x8*)(&Bs[cur ^ 1][c * 40 + part * 8]) = st[i];
            }
        }
        __syncthreads();
    }

    // ---- epilogue: direct stores; block covers full rows -> sectors fully dirtied ----
    #pragma unroll
    for (int ct = 0; ct < 10; ++ct) {
        const int col = colb + ct * 16 + r16;
        const float bv = (MODE == 2 && col < H) ? bias[col] : 0.f;
        #pragma unroll
        for (int s = 0; s < 4; ++s) {
            const int rowb = row0 + s * 16 + quad * 4;
            #pragma unroll
            for (int e = 0; e < 4; ++e) {
                const float v = acc[s][ct][e] + bv;
                const size_t off = (size_t)(rowb + e) * SB + col;
                if (MODE == 0) {
                    out8 [off] = (unsigned char)f16_to_fp8((_Float16)v);
                    out16[off] = (_Float16)(v > 0.f ? v : 0.f);
                } else if (MODE == 1) {
                    out16[off] = (_Float16)v;
                } else {
                    out16[off] = (_Float16)(v > 0.f ? v : 0.f);
                }
            }
        }
    }
}

// ---------------- aggregate: dst[a][:] = sum_k w_bonds[a2b[a][k]] * src[a2b[a][k]][:] ----------------
__global__ __launch_bounds__(256, 8) void aggregate_kernel(
    const _Float16* __restrict__ src,
    const int* __restrict__ a2b,
    const float* __restrict__ w_bonds,
    _Float16* __restrict__ dst)
{
    const int lane = threadIdx.x & 63;
    const int a = blockIdx.x * 4 + (threadIdx.x >> 6);
    if (a >= N_ATOMS || lane >= 40) return;
    const int h0 = lane * 8;
    float acc[8] = {0, 0, 0, 0, 0, 0, 0, 0};
    #pragma unroll
    for (int k = 0; k < MAX_NB; ++k) {
        const int b = a2b[a * MAX_NB + k];
        const float w = w_bonds[b];
        const f16x8 m = *(const f16x8*)(src + (size_t)b * SB + h0);
        #pragma unroll
        for (int j = 0; j < 8; ++j) acc[j] += w * (float)m[j];
    }
    f16x8 o;
    #pragma unroll
    for (int j = 0; j < 8; ++j) o[j] = (_Float16)acc[j];
    *(f16x8*)(dst + (size_t)a * SB + h0) = o;
}

// ---------------- bond update: msg[b] = relu(inp[b] + hm[b2a[b]] - w_b * hb[b2revb[b]]) ----------------
__global__ __launch_bounds__(256, 8) void update_kernel(
    const unsigned char* __restrict__ inp8,
    const _Float16* __restrict__ hm,
    const _Float16* __restrict__ hb,
    const int* __restrict__ b2a,
    const int* __restrict__ b2revb,
    const float* __restrict__ w_bonds,
    _Float16* __restrict__ msg)
{
    const int lane = threadIdx.x & 63;
    const int b = blockIdx.x * 4 + (threadIdx.x >> 6);
    if (b >= MB_P || lane >= 40) return;
    const bool real = b < N_BONDS;
    const int bc = real ? b : 0;
    const int a  = b2a[bc];
    const int rb = b2revb[bc];
    const float w = w_bonds[bc];
    const int h0 = lane * 8;
    const uint2 i8  = *(const uint2*)(inp8 + (size_t)b * SB + h0);
    const f16x8 hmv = *(const f16x8*)(hm + (size_t)a  * SB + h0);
    const f16x8 hbv = *(const f16x8*)(hb + (size_t)rb * SB + h0);
    f16x8 o;
    #pragma unroll
    for (int j = 0; j < 8; ++j) {
        const unsigned int c = ((j < 4 ? i8.x : i8.y) >> (8 * (j & 3))) & 255u;
        const float v = fp8_to_f32(c) + (float)hmv[j] - w * (float)hbv[j];
        o[j] = (_Float16)((real && v > 0.f) ? v : 0.f);
    }
    *(f16x8*)(msg + (size_t)b * SB + h0) = o;
}

// ---------------- readout ----------------
__global__ __launch_bounds__(256, 8) void readout_kernel(
    const _Float16* __restrict__ ah,
    const float* __restrict__ w_atoms,
    const float* __restrict__ dop,
    float* __restrict__ out)
{
    const int lane = threadIdx.x & 63;
    const int m = blockIdx.x * 4 + (threadIdx.x >> 6);
    if (m >= N_MOLS || lane >= 40) return;
    const int h0 = lane * 8;
    const int a0 = 1 + m * APM;
    float acc[8] = {0, 0, 0, 0, 0, 0, 0, 0};
    float wsum = 0.f;
    for (int i = 0; i < APM; ++i) {
        const float w = w_atoms[a0 + i];
        wsum += w;
        const f16x8 v = *(const f16x8*)(ah + (size_t)(a0 + i) * SB + h0);
        #pragma unroll
        for (int j = 0; j < 8; ++j) acc[j] += w * (float)v[j];
    }
    const float s = dop[m] / wsum;
    #pragma unroll
    for (int j = 0; j < 8; ++j) {
        const int h = h0 + j;
        if (h < H) out[(size_t)m * H + h] = s * acc[j];
    }
}

// ---------------- launch ----------------
extern "C" void kernel_launch(void* const* d_in, const int* in_sizes, int n_in,
                              void* d_out, int out_size, void* d_ws, size_t ws_size,
                              hipStream_t stream) {
    const float* f_atoms = (const float*)d_in[0];
    const float* f_bonds = (const float*)d_in[1];
    const float* w_atoms = (const float*)d_in[2];
    const float* w_bonds = (const float*)d_in[3];
    const float* dop     = (const float*)d_in[4];
    const float* W_i     = (const float*)d_in[5];
    const float* W_h     = (const float*)d_in[6];
    const float* W_o     = (const float*)d_in[7];
    const float* b_o     = (const float*)d_in[8];
    const int* a2b    = (const int*)d_in[9];
    const int* b2a    = (const int*)d_in[10];
    const int* b2revb = (const int*)d_in[11];
    float* out = (float*)d_out;

    char* p = (char*)d_ws;
    auto alloc = [&](size_t bytes) {
        char* q = p;
        p += ((bytes + 64 + 255) / 256) * 256;
        return q;
    };
    unsigned char* inp8 = (unsigned char*)alloc((size_t)MB_P * SB);          // 64.1 MB
    _Float16* msg  = (_Float16*)alloc((size_t)MB_P * SB * 2);                // 128.1 MB
    _Float16* hb   = (_Float16*)alloc((size_t)MB_P * SB * 2);                // 128.1 MB
    _Float16* hm   = (_Float16*)alloc((size_t)MA_P * SB * 2);                // 64.1 MB
    _Float16* Wth  = (_Float16*)alloc((size_t)320 * SWH * 2);
    _Float16* Wti  = (_Float16*)alloc((size_t)320 * SWI * 2);
    _Float16* Wto  = (_Float16*)alloc((size_t)320 * SWO * 2);                // total ~385 MB
    _Float16* fb16 = hb;                    // fb16 (64 MB) lives in hb until first layer GEMM
    _Float16* fa16 = (_Float16*)inp8;       // fa16 (32 MB) lives in inp8 after last update
    _Float16* ah   = hb;                    // output-GEMM result reuses dead hb

    if ((size_t)(p - (char*)d_ws) > ws_size) {   // clean failure instead of fault
        hipMemsetAsync(d_out, 0, (size_t)out_size * sizeof(float), stream);
        return;
    }

    // casts
    {
        unsigned n1 = (unsigned)MB_P * SF;
        cast_fb_kernel<<<(n1 + 255) / 256, 256, 0, stream>>>(f_bonds, fb16);
        cast_wh_kernel<<<(320 * SWH + 255) / 256, 256, 0, stream>>>(W_h, Wth);
        cast_wi_kernel<<<(320 * SWI + 255) / 256, 256, 0, stream>>>(W_i, Wti);
        cast_wo_kernel<<<(320 * SWO + 255) / 256, 256, 0, stream>>>(W_o, Wto);
    }

    const int gB = MB_P / 128;            // 1564
    const int gA = MA_P / 128;            // 782
    const int aggGrid = (N_ATOMS + 3) / 4;
    const int updGrid = MB_P / 4;

    // inp = fb @ W_i (fp8, pre-relu), msg0 = relu(inp)
    dgemm_kernel<5, 0><<<gB, 256, 0, stream>>>(fb16, nullptr, Wti, nullptr, msg, inp8);
    for (int d = 0; d < 3; ++d) {
        // hb = msg @ W_h  (dense, linear)
        dgemm_kernel<10, 1><<<gB, 256, 0, stream>>>(msg, nullptr, Wth, nullptr, hb, nullptr);
        // hm[a] = sum w * hb[a2b]
        aggregate_kernel<<<aggGrid, 256, 0, stream>>>(hb, a2b, w_bonds, hm);
        // msg = relu(inp + hm[b2a] - w * hb[b2revb])   (in place)
        update_kernel<<<updGrid, 256, 0, stream>>>(inp8, hm, hb, b2a, b2revb, w_bonds, msg);
    }
    // final atom aggregation from msg
    aggregate_kernel<<<aggGrid, 256, 0, stream>>>(msg, a2b, w_bonds, hm);
    // fa cast into (dead) inp8 region
    {
        unsigned n2 = (unsigned)MA_P * SF;
        cast_fa_kernel<<<(n2 + 255) / 256, 256, 0, stream>>>(f_atoms, fa16);
    }
    // ah = relu([hm | fa] @ W_o + b_o)
    dgemm_kernel<15, 2><<<gA, 256, 0, stream>>>(hm, fa16, Wto, b_o, ah, nullptr);
    readout_kernel<<<(N_MOLS + 3) / 4, 256, 0, stream>>>(ah, w_atoms, dop, out);
}